// Round 17
// baseline (164.663 us; speedup 1.0000x reference)
//
#include <hip/hip_runtime.h>
#include <hip/hip_bf16.h>

// SelfAttention: x[8,256,48,48] fp32; wq/wk/wv[256,256] fp32.
// out = x + attn(softmax(q^T k), v). B=8, C=256, N=2304. fp16 MFMA path.
//
// R16 post-mortem: permlane+setprio neutral; phases run sequentially on
// different pipes (QK^T MFMA ~320cy, SM VALU ~250cy, pack+PV ~150cy summed).
// R17 (T15 double-pipeline): compute QK^T(t+1) concurrently with SM(t).
// Loop: vf(t); stageK(t+2); vmcnt(4); s_barrier; d=dnxt; dnxt=QK^T(t+1);
// SM(t)||; pack; PV(t). Barrier moved mid-iter (count unchanged); explicit
// vmcnt(4) + barrier makes buf(t+1) cross-wave safe (in-order vmcnt: vf(t)
// issued after stageK(t+1)). Slot overwrite separated by 1 barrier. d x2
// state: +16 regs -> ~192 unified, still 2 waves/SIMD.
//
// K_swz[kb][ks 16][hi 2][key 32][j 8]: short off = kb*8192+ks*512+hi*256+key*8+j
// V_swz[kb][ct 8][kh 2][hi 2][c 32][j 8]: off = kb*8192+ct*1024+kh*512+hi*256+c*8+j
// weights frag-ordered: off = ot*4096 + ks*512 + g*128 + i*8 + j
// ws: wq/wk/wv fp16 [65536 ea]; Qt [B*N*C] token-major; Ksw,Vsw [B*N*C];
//     P fp16 [splits][B][C][N]; ml f32 [splits][B][N][2].

#define DEVI __device__ __forceinline__

typedef _Float16 f16x8 __attribute__((ext_vector_type(8)));
typedef float f32x4 __attribute__((ext_vector_type(4)));
typedef float f32x16 __attribute__((ext_vector_type(16)));

constexpr int Bn = 8, Cn = 256, Nn = 48 * 48;   // 2304

#if defined(__has_builtin)
#if __has_builtin(__builtin_amdgcn_permlane32_swap)
#define HAVE_PL32 1
#endif
#endif

DEVI unsigned short f2h(float f) {
  _Float16 h = (_Float16)f;
  return __builtin_bit_cast(unsigned short, h);
}
DEVI float h2f(unsigned short u) {
  return (float)__builtin_bit_cast(_Float16, u);
}
DEVI unsigned pk2(float a, float b) {           // pack 2 f32 -> f16x2 (RTZ)
  auto h = __builtin_amdgcn_cvt_pkrtz(a, b);
  return __builtin_bit_cast(unsigned, h);
}
DEVI void stage16(const unsigned short* g, unsigned short* l) {
  __builtin_amdgcn_global_load_lds(
      (const __attribute__((address_space(1))) void*)g,
      (__attribute__((address_space(3))) void*)l, 16, 0, 0);
}
// permlane32_swap(a,b): a' = {a.lo, b.lo}; b' = {a.hi, b.hi}
DEVI void pl32swap(unsigned& a, unsigned& b) {
#ifdef HAVE_PL32
  auto r = __builtin_amdgcn_permlane32_swap(a, b, false, false);
  a = r[0];
  b = r[1];
#else
  unsigned sa = __shfl_xor(a, 32), sb = __shfl_xor(b, 32);
  bool hb = (threadIdx.x & 32) != 0;
  a = hb ? sb : a;
  b = hb ? b : sa;
#endif
}
DEVI void pl32swapf(float& a, float& b) {
  unsigned ua = __builtin_bit_cast(unsigned, a);
  unsigned ub = __builtin_bit_cast(unsigned, b);
  pl32swap(ua, ub);
  a = __builtin_bit_cast(float, ua);
  b = __builtin_bit_cast(float, ub);
}

#define MFMA16(a, b, c) __builtin_amdgcn_mfma_f32_16x16x32_f16((a), (b), (c), 0, 0, 0)
#define MFMA32(a, b, c) __builtin_amdgcn_mfma_f32_32x32x16_f16((a), (b), (c), 0, 0, 0)

// ---- weights -> fp16, FRAG-ORDERED: dst[ot*4096 + ks*512 + g*128 + i*8 + j]
//      = w[oc = 16ot + i][c = 32ks + 8g + j]  (wq pre-scaled by log2e)
__global__ __launch_bounds__(256) void cvt_w(const float* __restrict__ wq,
                                             const float* __restrict__ wk,
                                             const float* __restrict__ wv,
                                             unsigned short* __restrict__ o) {
  int idx = blockIdx.x * 256 + threadIdx.x;     // 3*65536 total
  int mat = idx >> 16, off = idx & 65535;
  const float* s = (mat == 0) ? wq : (mat == 1) ? wk : wv;
  int ot = off >> 12, ks = (off >> 9) & 7, g = (off >> 7) & 3;
  int i = (off >> 3) & 15, j = off & 7;
  float v = s[(ot * 16 + i) * Cn + ks * 32 + g * 8 + j];
  if (mat == 0) v *= 1.44269504f;               // exp2-domain softmax
  o[idx] = f2h(v);
}

// ---------------- QKV projection (z-merged, n-tile 32, frag-ordered w) -----
// grid (N/32, B) = (72, 8), 256 thr = 4 waves. th = w&1 (token half).
__global__ __launch_bounds__(256) void qkv_proj(
    const float* __restrict__ x,
    const unsigned short* __restrict__ wqb, const unsigned short* __restrict__ wkb,
    const unsigned short* __restrict__ wvb,
    unsigned short* __restrict__ Qt, unsigned short* __restrict__ Ksw,
    unsigned short* __restrict__ Vsw) {
  __shared__ unsigned short xT[32][264];        // [token][c], +8 pad
  const int tid = threadIdx.x;
  const int n0 = blockIdx.x * 32;
  const int b = blockIdx.y;
  const float* xb = x + (size_t)b * Cn * Nn;
  {
    int c0 = tid >> 3;
    int nn = (tid & 7) * 4;
#pragma unroll
    for (int it = 0; it < 8; ++it) {
      int c = c0 + 32 * it;
      float4 v = *(const float4*)(xb + (size_t)c * Nn + n0 + nn);
      xT[nn + 0][c] = f2h(v.x);
      xT[nn + 1][c] = f2h(v.y);
      xT[nn + 2][c] = f2h(v.z);
      xT[nn + 3][c] = f2h(v.w);
    }
  }
  __syncthreads();
  const int lane = tid & 63, w = tid >> 6;
  const int i = lane & 15, g = lane >> 4;
  const int th = w & 1;                         // token half (constant both phases)
  const int wlo = g * 128 + i * 8;              // frag-ordered lane offset
  f16x8 xf[8];                                  // x^T frags for tokens th*16..+15
#pragma unroll
  for (int ks = 0; ks < 8; ++ks)
    xf[ks] = *(const f16x8*)(&xT[th * 16 + i][32 * ks + 8 * g]);

  const int kb0 = n0 >> 5;                      // == blockIdx.x (32-token chunk)
  // ---- phase 1: Q (w<2) or K (w>=2), 16 ot-tiles ----
  if (w < 2) {                                  // Q -> token-major [N][C]
    const size_t tokbase = (size_t)b * Nn + n0 + th * 16;
    for (int ot = 0; ot < 16; ++ot) {
      f32x4 acc = {0.f, 0.f, 0.f, 0.f};
      const unsigned short* wr = wqb + ot * 4096 + wlo;
#pragma unroll
      for (int ks = 0; ks < 8; ++ks)
        acc = MFMA16(xf[ks], *(const f16x8*)(wr + 512 * ks), acc);
#pragma unroll
      for (int r = 0; r < 4; ++r)
        Qt[(tokbase + 4 * g + r) * Cn + ot * 16 + i] = f2h(acc[r]);
    }
  } else {                                      // K -> frag-swizzled
    unsigned short* kout = Ksw + (size_t)b * Nn * Cn + (size_t)kb0 * 8192
                         + ((i >> 3) & 1) * 256 + (i & 7);
    const int keyb = th * 16 + 4 * g;           // + r
    for (int ot = 0; ot < 16; ++ot) {
      f32x4 acc = {0.f, 0.f, 0.f, 0.f};
      const unsigned short* wr = wkb + ot * 4096 + wlo;
#pragma unroll
      for (int ks = 0; ks < 8; ++ks)
        acc = MFMA16(xf[ks], *(const f16x8*)(wr + 512 * ks), acc);
#pragma unroll
      for (int r = 0; r < 4; ++r)
        kout[ot * 512 + (keyb + r) * 8] = f2h(acc[r]);
    }
  }
  // ---- phase 2: V, 8 ot-tiles per wave; acc[r]=V[c=ot*16+4g+r][tok=th*16+i]
  {
    unsigned short* vout = Vsw + (size_t)b * Nn * Cn + (size_t)kb0 * 8192
                         + th * 512 + ((i >> 3) & 1) * 256 + (i & 7);
    const int otb = (w >> 1) * 8;
    for (int oo = 0; oo < 8; ++oo) {
      const int ot = otb + oo;
      f32x4 acc = {0.f, 0.f, 0.f, 0.f};
      const unsigned short* wr = wvb + ot * 4096 + wlo;
#pragma unroll
      for (int ks = 0; ks < 8; ++ks)
        acc = MFMA16(*(const f16x8*)(wr + 512 * ks), xf[ks], acc);
#pragma unroll
      for (int r = 0; r < 4; ++r) {
        int c = ot * 16 + 4 * g + r;
        vout[(c >> 5) * 1024 + (c & 31) * 8] = f2h(acc[r]);
      }
    }
  }
}

// ---- flash attention: split-K, K 3-buf LDS, V reg-streamed, T15 pipeline --
// grid Bn*splits*36, 256 thr = 4 waves = 2 q-tiles(32q) x 2 c-halves(128c).
// LDS 48KB = 3 x 16KB K bufs, staged 2-ahead. One mid-iter barrier after
// explicit vmcnt(4) (confirms buf(t+1) block-wide). QK^T(t+1) overlaps SM(t).
__global__ __launch_bounds__(256, 2) void attn_split(
    const unsigned short* __restrict__ Qt, const unsigned short* __restrict__ Ksw,
    const unsigned short* __restrict__ Vsw,
    unsigned short* __restrict__ P, float* __restrict__ ml, int splits) {
  __shared__ unsigned short smem[24576];        // 48 KB
  const int nblk = gridDim.x;                   // divisible by 8
  const int cpx = nblk >> 3;
  const int swz = (blockIdx.x & 7) * cpx + (blockIdx.x >> 3);  // XCD chunked
  const int per_b = splits * 36;
  const int b = swz / per_b;
  const int rem = swz - b * per_b;
  const int s = rem / 36;
  const int qt = rem - s * 36;
  const int n0 = qt * 64;
  const int kn = Nn / splits;
  const int kb0 = (s * kn) >> 5;                // first 32-key chunk id
  const int NT = kn / 32;                       // >= 18

  const int tid = threadIdx.x, lane = tid & 63, w = tid >> 6;
  const int q = lane & 31, hi = lane >> 5;
  const int qtile = w & 1, chalf = w >> 1;
  const int q0 = n0 + qtile * 32;

  const unsigned short* Ksrc = Ksw + (size_t)b * Nn * Cn + tid * 8;
  const unsigned short* Vb = Vsw + (size_t)b * Nn * Cn + hi * 256 + q * 8
                           + (size_t)chalf * 4096;

  auto stageK = [&](int kbid, int buf) {        // linear 16KB chunk copy
    unsigned short* dst = smem + buf * 8192 + w * 512;
    const unsigned short* src = Ksrc + (size_t)kbid * 8192;
#pragma unroll
    for (int c4 = 0; c4 < 4; ++c4)
      stage16(src + c4 * 2048, dst + c4 * 2048);
  };

  const int lo = hi * 512 + q * 16;             // byte offset within frag row
  auto qkt = [&](int buf, const f16x8* qf) -> f32x16 {
    const char* KsB = (const char*)smem + buf * 16384;
    f32x16 da = (f32x16)(0.f), db = (f32x16)(0.f);
#pragma unroll
    for (int ks = 0; ks < 8; ++ks) {
      da = MFMA32(*(const f16x8*)(KsB + ks * 1024 + lo), qf[ks], da);
      db = MFMA32(*(const f16x8*)(KsB + (ks + 8) * 1024 + lo), qf[ks + 8], db);
    }
    return da + db;
  };

  // resident Q B-frags: lane: query=q, c = 16*ks + 8*hi + j
  const unsigned short* Qb = Qt + ((size_t)b * Nn + q0 + q) * Cn + 8 * hi;
  f16x8 qf[16];
#pragma unroll
  for (int ks = 0; ks < 16; ++ks) qf[ks] = *(const f16x8*)(Qb + 16 * ks);

  stageK(kb0, 0);                               // prologue: 2-ahead
  stageK(kb0 + 1, 1);

  f32x16 acc[4];                                // channels chalf*128 .. +128
#pragma unroll
  for (int ct = 0; ct < 4; ++ct) acc[ct] = (f32x16)(0.f);
  float m = -1e30f, lsum = 0.f;                 // lsum: per-half partial

  asm volatile("s_waitcnt vmcnt(4)" ::: "memory");   // own K0 landed (K1 in flight)
  __builtin_amdgcn_sched_barrier(0);
  __builtin_amdgcn_s_barrier();                 // all waves' K0 landed
  f32x16 dnxt = qkt(0, qf);                     // scores for tile 0

  for (int t = 0; t < NT; ++t) {
    const unsigned short* vp = Vb + (size_t)(kb0 + t) * 8192;
    // ---- V frags for this iter: all 8, issued first ----
    f16x8 vf[8];
#pragma unroll
    for (int ct = 0; ct < 4; ++ct) {
      vf[2 * ct] = *(const f16x8*)(vp + ct * 1024);
      vf[2 * ct + 1] = *(const f16x8*)(vp + ct * 1024 + 512);
    }
    __builtin_amdgcn_sched_barrier(0);          // keep V issues before K stage
    if (t + 2 < NT) stageK(kb0 + t + 2, (t + 2) % 3);

    // vmcnt(4): confirms vf(t) + stageK(t+1) (in-order); leaves stageK(t+2).
    asm volatile("s_waitcnt vmcnt(4)" ::: "memory");
    __builtin_amdgcn_sched_barrier(0);
    __builtin_amdgcn_s_barrier();               // buf(t+1) now block-wide safe

    f32x16 d = dnxt;
    // ---- QK^T(t+1) on MFMA pipe, overlapped with SM(t) on VALU pipe ----
    if (t + 1 < NT) dnxt = qkt((t + 1) % 3, qf);

    // ---- online softmax (log2 domain) on d = scores(t) ----
    float u0 = fmaxf(d[0], d[1]),   u1 = fmaxf(d[2], d[3]);
    float u2 = fmaxf(d[4], d[5]),   u3 = fmaxf(d[6], d[7]);
    float u4 = fmaxf(d[8], d[9]),   u5 = fmaxf(d[10], d[11]);
    float u6 = fmaxf(d[12], d[13]), u7 = fmaxf(d[14], d[15]);
    float mx = fmaxf(fmaxf(fmaxf(u0, u1), fmaxf(u2, u3)),
                     fmaxf(fmaxf(u4, u5), fmaxf(u6, u7)));
    {                                           // cross-half max (order-robust)
      float mc = mx;
      pl32swapf(mc, mx);
      mx = fmaxf(mc, mx);
    }
    if (__any(mx > m + 12.f)) {                 // defer-max (THR=12 log2)
      float mnew = fmaxf(m, mx);
      float alpha = __builtin_exp2f(m - mnew);
      m = mnew;
      lsum *= alpha;
#pragma unroll
      for (int ct = 0; ct < 4; ++ct)
#pragma unroll
        for (int r = 0; r < 16; ++r) acc[ct][r] *= alpha;
    }
    float p[16];
#pragma unroll
    for (int r = 0; r < 16; ++r) p[r] = __builtin_exp2f(d[r] - m);
    float cs = 0.f;
#pragma unroll
    for (int r = 0; r < 16; ++r) cs += p[r];
    lsum += cs;                                 // per-half partial (no shfl)

    // ---- P -> B-frags: swap(A0,A2) yields (pb0.u[0], pb0.u[2]) etc ----
    unsigned A0 = pk2(p[0], p[1]), A1 = pk2(p[2], p[3]);
    unsigned A2 = pk2(p[4], p[5]), A3 = pk2(p[6], p[7]);
    unsigned A4 = pk2(p[8], p[9]), A5 = pk2(p[10], p[11]);
    unsigned A6 = pk2(p[12], p[13]), A7 = pk2(p[14], p[15]);
    pl32swap(A0, A2);
    pl32swap(A1, A3);
    pl32swap(A4, A6);
    pl32swap(A5, A7);
    union { unsigned u[4]; f16x8 v; } pb0, pb1;
    pb0.u[0] = A0; pb0.u[1] = A1; pb0.u[2] = A2; pb0.u[3] = A3;
    pb1.u[0] = A4; pb1.u[1] = A5; pb1.u[2] = A6; pb1.u[3] = A7;

    // ---- PV: 4 c-tiles of this wave's c-half, V from registers ----
    __builtin_amdgcn_s_setprio(1);
    acc[0] = MFMA32(vf[0], pb0.v, acc[0]);
    acc[0] = MFMA32(vf[1], pb1.v, acc[0]);
    acc[1] = MFMA32(vf[2], pb0.v, acc[1]);
    acc[1] = MFMA32(vf[3], pb1.v, acc[1]);
    acc[2] = MFMA32(vf[4], pb0.v, acc[2]);
    acc[2] = MFMA32(vf[5], pb1.v, acc[2]);
    acc[3] = MFMA32(vf[6], pb0.v, acc[3]);
    acc[3] = MFMA32(vf[7], pb1.v, acc[3]);
    __builtin_amdgcn_s_setprio(0);
  }

  // ---- epilogue: combine half-sums (order-robust), O_s = acc/lsum ----
  {
    float lc = lsum;
    pl32swapf(lc, lsum);
    lsum += lc;
  }
  const float rl = 1.f / lsum;
  unsigned short* Pb = P + (size_t)(s * Bn + b) * Cn * Nn;
#pragma unroll
  for (int ct = 0; ct < 4; ++ct)
#pragma unroll
    for (int r = 0; r < 16; ++r) {
      int c = 32 * (chalf * 4 + ct) + (r & 3) + 8 * (r >> 2) + 4 * hi;
      Pb[(size_t)c * Nn + q0 + q] = f2h(acc[ct][r] * rl);
    }
  if (!hi && !chalf)
    *(float2*)&ml[((size_t)(s * Bn + b) * Nn + q0 + q) * 2] = make_float2(m, lsum);
}

// ---------------- combine partials + residual ----------------
// out = x + sum_s w_s * O_s,  w_s = 2^(m_s - M) * l_s / sum(2^(m_s-M) l_s).
__global__ __launch_bounds__(256) void combine_k(
    const float* __restrict__ x, const unsigned short* __restrict__ P,
    const float* __restrict__ ml, float* __restrict__ out, int splits) {
  __shared__ float sc[4][32];
  const int tpb = Nn / 32;                      // 72
  const int b = blockIdx.x / tpb;
  const int n0 = (blockIdx.x - b * tpb) * 32;
  const int t = threadIdx.x;
  if (t < 32) {
    const int n = n0 + t;
    const size_t sstr = (size_t)Bn * Nn * 2;
    const float* mlb = ml + ((size_t)b * Nn + n) * 2;
    float m0 = mlb[0], l0 = mlb[1];
    float m1 = -1e30f, l1 = 0.f, m2 = -1e30f, l2 = 0.f, m3 = -1e30f, l3 = 0.f;
    if (splits > 1) { m1 = mlb[sstr]; l1 = mlb[sstr + 1]; }
    if (splits > 2) { m2 = mlb[2 * sstr]; l2 = mlb[2 * sstr + 1]; }
    if (splits > 3) { m3 = mlb[3 * sstr]; l3 = mlb[3 * sstr + 1]; }
    float M = fmaxf(fmaxf(m0, m1), fmaxf(m2, m3));
    float g0 = __builtin_exp2f(m0 - M) * l0, g1 = __builtin_exp2f(m1 - M) * l1;
    float g2 = __builtin_exp2f(m2 - M) * l2, g3 = __builtin_exp2f(m3 - M) * l3;
    float rden = 1.f / (g0 + g1 + g2 + g3);
    sc[0][t] = g0 * rden; sc[1][t] = g1 * rden;
    sc[2][t] = g2 * rden; sc[3][t] = g3 * rden;
  }
  __syncthreads();
  const int nl4 = (t & 7) * 4, c0 = t >> 3;
  const size_t pstr = (size_t)Bn * Cn * Nn;     // shorts per split
  const float* xb = x + (size_t)b * Cn * Nn;
  float* ob = out + (size_t)b * Cn * Nn;
#pragma unroll
  for (int k = 0; k < 8; ++k) {
    const int c = c0 + 32 * k;
    const unsigned short* Pp = P + ((size_t)b * Cn + c) * Nn + n0 + nl4;
    f32x4 a = {0.f, 0.f, 0.f, 0.f};
    for (int s2 = 0; s2 < splits; ++s2) {
      ushort4 ph = *(const ushort4*)(Pp + s2 * pstr);
      f32x4 pv = {h2f(ph.x), h2f(ph.y), h2f(ph.z), h2f(ph.w)};
      f32x4 sw = {sc[s2][nl4 + 0], sc[s2][nl4 + 1], sc[s2][nl4 + 2], sc[s2][nl4 + 3]};
      a += sw * pv;
    }
    f32x4 xv = *(const f32x4*)(xb + (size_t)c * Nn + n0 + nl4);
    *(f32x4*)(ob + (size_t)c * Nn + n0 + nl4) = xv + a;
  }
}

extern "C" void kernel_launch(void* const* d_in, const int* in_sizes, int n_in,
                              void* d_out, int out_size, void* d_ws, size_t ws_size,
                              hipStream_t stream) {
  const float* x = (const float*)d_in[0];
  const float* wq = (const float*)d_in[1];
  const float* wk = (const float*)d_in[2];
  const float* wv = (const float*)d_in[3];
  float* out = (float*)d_out;

  unsigned short* wqb = (unsigned short*)d_ws;
  unsigned short* wkb = wqb + Cn * Cn;
  unsigned short* wvb = wkb + Cn * Cn;
  unsigned short* Qt = wvb + Cn * Cn;
  unsigned short* Ksw = Qt + (size_t)Bn * Nn * Cn;
  unsigned short* Vsw = Ksw + (size_t)Bn * Nn * Cn;
  unsigned short* P = Vsw + (size_t)Bn * Nn * Cn;

  const size_t baseB = (size_t)(3 * Cn * Cn + 3 * (size_t)Bn * Nn * Cn) * 2;
  const size_t perSplitB = (size_t)Bn * Nn * Cn * 2 + (size_t)Bn * Nn * 2 * 4;

  int splits = 1;
  if (baseB + 4 * perSplitB <= ws_size) splits = 4;
  else if (baseB + 2 * perSplitB <= ws_size) splits = 2;

  float* ml = (float*)(P + (size_t)splits * Bn * Nn * Cn);

  hipLaunchKernelGGL(cvt_w, dim3(3 * Cn * Cn / 256), dim3(256), 0, stream, wq, wk, wv, wqb);
  hipLaunchKernelGGL(qkv_proj, dim3(Nn / 32, Bn), dim3(256), 0, stream,
                     x, wqb, wkb, wvb, Qt, Ksw, Vsw);
  hipLaunchKernelGGL(attn_split, dim3(Bn * splits * 36), dim3(256), 0, stream,
                     Qt, Ksw, Vsw, P, ml, splits);
  hipLaunchKernelGGL(combine_k, dim3(Bn * Nn / 32), dim3(256), 0, stream,
                     x, P, ml, out, splits);
}

// Round 18
// 163.331 us; speedup vs baseline: 1.0082x; 1.0082x over previous
//
#include <hip/hip_runtime.h>
#include <hip/hip_bf16.h>

// SelfAttention: x[8,256,48,48] fp32; wq/wk/wv[256,256] fp32.
// out = x + attn(softmax(q^T k), v). B=8, C=256, N=2304. fp16 MFMA path.
//
// R17 post-mortem: T15 overlap helped (+2%) but added VALU bookkeeping:
// 32 zero-movs (da/db) + 16 adds (da+db) + 16 movs (d=dnxt) per iter.
// R18: (1) single-chain qkt (latency now hidden by T15 overlap + 2nd block);
// (2) unroll-by-2 ping-pong dA/dB (NT=18 even) removes the d copy.
// ~48 fewer VALU ops/iter; sync structure and numerics identical to R17.
//
// K_swz[kb][ks 16][hi 2][key 32][j 8]: short off = kb*8192+ks*512+hi*256+key*8+j
// V_swz[kb][ct 8][kh 2][hi 2][c 32][j 8]: off = kb*8192+ct*1024+kh*512+hi*256+c*8+j
// weights frag-ordered: off = ot*4096 + ks*512 + g*128 + i*8 + j
// ws: wq/wk/wv fp16 [65536 ea]; Qt [B*N*C] token-major; Ksw,Vsw [B*N*C];
//     P fp16 [splits][B][C][N]; ml f32 [splits][B][N][2].

#define DEVI __device__ __forceinline__

typedef _Float16 f16x8 __attribute__((ext_vector_type(8)));
typedef float f32x4 __attribute__((ext_vector_type(4)));
typedef float f32x16 __attribute__((ext_vector_type(16)));

constexpr int Bn = 8, Cn = 256, Nn = 48 * 48;   // 2304

#if defined(__has_builtin)
#if __has_builtin(__builtin_amdgcn_permlane32_swap)
#define HAVE_PL32 1
#endif
#endif

DEVI unsigned short f2h(float f) {
  _Float16 h = (_Float16)f;
  return __builtin_bit_cast(unsigned short, h);
}
DEVI float h2f(unsigned short u) {
  return (float)__builtin_bit_cast(_Float16, u);
}
DEVI unsigned pk2(float a, float b) {           // pack 2 f32 -> f16x2 (RTZ)
  auto h = __builtin_amdgcn_cvt_pkrtz(a, b);
  return __builtin_bit_cast(unsigned, h);
}
DEVI void stage16(const unsigned short* g, unsigned short* l) {
  __builtin_amdgcn_global_load_lds(
      (const __attribute__((address_space(1))) void*)g,
      (__attribute__((address_space(3))) void*)l, 16, 0, 0);
}
// permlane32_swap(a,b): a' = {a.lo, b.lo}; b' = {a.hi, b.hi}
DEVI void pl32swap(unsigned& a, unsigned& b) {
#ifdef HAVE_PL32
  auto r = __builtin_amdgcn_permlane32_swap(a, b, false, false);
  a = r[0];
  b = r[1];
#else
  unsigned sa = __shfl_xor(a, 32), sb = __shfl_xor(b, 32);
  bool hb = (threadIdx.x & 32) != 0;
  a = hb ? sb : a;
  b = hb ? b : sa;
#endif
}
DEVI void pl32swapf(float& a, float& b) {
  unsigned ua = __builtin_bit_cast(unsigned, a);
  unsigned ub = __builtin_bit_cast(unsigned, b);
  pl32swap(ua, ub);
  a = __builtin_bit_cast(float, ua);
  b = __builtin_bit_cast(float, ub);
}

#define MFMA16(a, b, c) __builtin_amdgcn_mfma_f32_16x16x32_f16((a), (b), (c), 0, 0, 0)
#define MFMA32(a, b, c) __builtin_amdgcn_mfma_f32_32x32x16_f16((a), (b), (c), 0, 0, 0)

// ---- weights -> fp16, FRAG-ORDERED: dst[ot*4096 + ks*512 + g*128 + i*8 + j]
//      = w[oc = 16ot + i][c = 32ks + 8g + j]  (wq pre-scaled by log2e)
__global__ __launch_bounds__(256) void cvt_w(const float* __restrict__ wq,
                                             const float* __restrict__ wk,
                                             const float* __restrict__ wv,
                                             unsigned short* __restrict__ o) {
  int idx = blockIdx.x * 256 + threadIdx.x;     // 3*65536 total
  int mat = idx >> 16, off = idx & 65535;
  const float* s = (mat == 0) ? wq : (mat == 1) ? wk : wv;
  int ot = off >> 12, ks = (off >> 9) & 7, g = (off >> 7) & 3;
  int i = (off >> 3) & 15, j = off & 7;
  float v = s[(ot * 16 + i) * Cn + ks * 32 + g * 8 + j];
  if (mat == 0) v *= 1.44269504f;               // exp2-domain softmax
  o[idx] = f2h(v);
}

// ---------------- QKV projection (z-merged, n-tile 32, frag-ordered w) -----
// grid (N/32, B) = (72, 8), 256 thr = 4 waves. th = w&1 (token half).
__global__ __launch_bounds__(256) void qkv_proj(
    const float* __restrict__ x,
    const unsigned short* __restrict__ wqb, const unsigned short* __restrict__ wkb,
    const unsigned short* __restrict__ wvb,
    unsigned short* __restrict__ Qt, unsigned short* __restrict__ Ksw,
    unsigned short* __restrict__ Vsw) {
  __shared__ unsigned short xT[32][264];        // [token][c], +8 pad
  const int tid = threadIdx.x;
  const int n0 = blockIdx.x * 32;
  const int b = blockIdx.y;
  const float* xb = x + (size_t)b * Cn * Nn;
  {
    int c0 = tid >> 3;
    int nn = (tid & 7) * 4;
#pragma unroll
    for (int it = 0; it < 8; ++it) {
      int c = c0 + 32 * it;
      float4 v = *(const float4*)(xb + (size_t)c * Nn + n0 + nn);
      xT[nn + 0][c] = f2h(v.x);
      xT[nn + 1][c] = f2h(v.y);
      xT[nn + 2][c] = f2h(v.z);
      xT[nn + 3][c] = f2h(v.w);
    }
  }
  __syncthreads();
  const int lane = tid & 63, w = tid >> 6;
  const int i = lane & 15, g = lane >> 4;
  const int th = w & 1;                         // token half (constant both phases)
  const int wlo = g * 128 + i * 8;              // frag-ordered lane offset
  f16x8 xf[8];                                  // x^T frags for tokens th*16..+15
#pragma unroll
  for (int ks = 0; ks < 8; ++ks)
    xf[ks] = *(const f16x8*)(&xT[th * 16 + i][32 * ks + 8 * g]);

  const int kb0 = n0 >> 5;                      // == blockIdx.x (32-token chunk)
  // ---- phase 1: Q (w<2) or K (w>=2), 16 ot-tiles ----
  if (w < 2) {                                  // Q -> token-major [N][C]
    const size_t tokbase = (size_t)b * Nn + n0 + th * 16;
    for (int ot = 0; ot < 16; ++ot) {
      f32x4 acc = {0.f, 0.f, 0.f, 0.f};
      const unsigned short* wr = wqb + ot * 4096 + wlo;
#pragma unroll
      for (int ks = 0; ks < 8; ++ks)
        acc = MFMA16(xf[ks], *(const f16x8*)(wr + 512 * ks), acc);
#pragma unroll
      for (int r = 0; r < 4; ++r)
        Qt[(tokbase + 4 * g + r) * Cn + ot * 16 + i] = f2h(acc[r]);
    }
  } else {                                      // K -> frag-swizzled
    unsigned short* kout = Ksw + (size_t)b * Nn * Cn + (size_t)kb0 * 8192
                         + ((i >> 3) & 1) * 256 + (i & 7);
    const int keyb = th * 16 + 4 * g;           // + r
    for (int ot = 0; ot < 16; ++ot) {
      f32x4 acc = {0.f, 0.f, 0.f, 0.f};
      const unsigned short* wr = wkb + ot * 4096 + wlo;
#pragma unroll
      for (int ks = 0; ks < 8; ++ks)
        acc = MFMA16(xf[ks], *(const f16x8*)(wr + 512 * ks), acc);
#pragma unroll
      for (int r = 0; r < 4; ++r)
        kout[ot * 512 + (keyb + r) * 8] = f2h(acc[r]);
    }
  }
  // ---- phase 2: V, 8 ot-tiles per wave; acc[r]=V[c=ot*16+4g+r][tok=th*16+i]
  {
    unsigned short* vout = Vsw + (size_t)b * Nn * Cn + (size_t)kb0 * 8192
                         + th * 512 + ((i >> 3) & 1) * 256 + (i & 7);
    const int otb = (w >> 1) * 8;
    for (int oo = 0; oo < 8; ++oo) {
      const int ot = otb + oo;
      f32x4 acc = {0.f, 0.f, 0.f, 0.f};
      const unsigned short* wr = wvb + ot * 4096 + wlo;
#pragma unroll
      for (int ks = 0; ks < 8; ++ks)
        acc = MFMA16(*(const f16x8*)(wr + 512 * ks), xf[ks], acc);
#pragma unroll
      for (int r = 0; r < 4; ++r) {
        int c = ot * 16 + 4 * g + r;
        vout[(c >> 5) * 1024 + (c & 31) * 8] = f2h(acc[r]);
      }
    }
  }
}

// ---- flash attention: split-K, K 3-buf LDS, V reg-streamed, T15 x2 --------
// grid Bn*splits*36, 256 thr = 4 waves = 2 q-tiles(32q) x 2 c-halves(128c).
// LDS 48KB = 3 x 16KB K bufs, staged 2-ahead. Mid-iter barrier after explicit
// vmcnt(4). QK^T(t+1) (single chain) overlaps SM(t); dA/dB ping-pong.
__global__ __launch_bounds__(256, 2) void attn_split(
    const unsigned short* __restrict__ Qt, const unsigned short* __restrict__ Ksw,
    const unsigned short* __restrict__ Vsw,
    unsigned short* __restrict__ P, float* __restrict__ ml, int splits) {
  __shared__ unsigned short smem[24576];        // 48 KB
  const int nblk = gridDim.x;                   // divisible by 8
  const int cpx = nblk >> 3;
  const int swz = (blockIdx.x & 7) * cpx + (blockIdx.x >> 3);  // XCD chunked
  const int per_b = splits * 36;
  const int b = swz / per_b;
  const int rem = swz - b * per_b;
  const int s = rem / 36;
  const int qt = rem - s * 36;
  const int n0 = qt * 64;
  const int kn = Nn / splits;
  const int kb0 = (s * kn) >> 5;                // first 32-key chunk id
  const int NT = kn / 32;                       // 18 at splits=4 (even)

  const int tid = threadIdx.x, lane = tid & 63, w = tid >> 6;
  const int q = lane & 31, hi = lane >> 5;
  const int qtile = w & 1, chalf = w >> 1;
  const int q0 = n0 + qtile * 32;

  const unsigned short* Ksrc = Ksw + (size_t)b * Nn * Cn + tid * 8;
  const unsigned short* Vb = Vsw + (size_t)b * Nn * Cn + hi * 256 + q * 8
                           + (size_t)chalf * 4096;

  auto stageK = [&](int kbid, int buf) {        // linear 16KB chunk copy
    unsigned short* dst = smem + buf * 8192 + w * 512;
    const unsigned short* src = Ksrc + (size_t)kbid * 8192;
#pragma unroll
    for (int c4 = 0; c4 < 4; ++c4)
      stage16(src + c4 * 2048, dst + c4 * 2048);
  };

  const int lo = hi * 512 + q * 16;             // byte offset within frag row

  // resident Q B-frags: lane: query=q, c = 16*ks + 8*hi + j
  const unsigned short* Qb = Qt + ((size_t)b * Nn + q0 + q) * Cn + 8 * hi;
  f16x8 qf[16];
#pragma unroll
  for (int ks = 0; ks < 16; ++ks) qf[ks] = *(const f16x8*)(Qb + 16 * ks);

  auto qkt = [&](int buf) -> f32x16 {           // single-chain QK^T
    const char* KsB = (const char*)smem + buf * 16384;
    f32x16 dd = (f32x16)(0.f);
#pragma unroll
    for (int ks = 0; ks < 16; ++ks)
      dd = MFMA32(*(const f16x8*)(KsB + ks * 1024 + lo), qf[ks], dd);
    return dd;
  };

  stageK(kb0, 0);                               // prologue: 2-ahead
  stageK(kb0 + 1, 1);

  f32x16 acc[4];                                // channels chalf*128 .. +128
#pragma unroll
  for (int ct = 0; ct < 4; ++ct) acc[ct] = (f32x16)(0.f);
  float m = -1e30f, lsum = 0.f;                 // lsum: per-half partial

  asm volatile("s_waitcnt vmcnt(4)" ::: "memory");   // own K0 landed (K1 in flight)
  __builtin_amdgcn_sched_barrier(0);
  __builtin_amdgcn_s_barrier();                 // all waves' K0 landed

  auto body = [&](int t, f32x16& dcur, f32x16& dnx) {
    const unsigned short* vp = Vb + (size_t)(kb0 + t) * 8192;
    // ---- V frags for this iter: all 8, issued first ----
    f16x8 vf[8];
#pragma unroll
    for (int ct = 0; ct < 4; ++ct) {
      vf[2 * ct] = *(const f16x8*)(vp + ct * 1024);
      vf[2 * ct + 1] = *(const f16x8*)(vp + ct * 1024 + 512);
    }
    __builtin_amdgcn_sched_barrier(0);          // keep V issues before K stage
    if (t + 2 < NT) stageK(kb0 + t + 2, (t + 2) % 3);

    // vmcnt(4): confirms vf(t) + stageK(t+1) (in-order); leaves stageK(t+2).
    asm volatile("s_waitcnt vmcnt(4)" ::: "memory");
    __builtin_amdgcn_sched_barrier(0);
    __builtin_amdgcn_s_barrier();               // buf(t+1) now block-wide safe

    // ---- QK^T(t+1) on MFMA pipe, overlapped with SM(t) on VALU pipe ----
    if (t + 1 < NT) dnx = qkt((t + 1) % 3);

    // ---- online softmax (log2 domain) on dcur = scores(t) ----
    float u0 = fmaxf(dcur[0], dcur[1]),   u1 = fmaxf(dcur[2], dcur[3]);
    float u2 = fmaxf(dcur[4], dcur[5]),   u3 = fmaxf(dcur[6], dcur[7]);
    float u4 = fmaxf(dcur[8], dcur[9]),   u5 = fmaxf(dcur[10], dcur[11]);
    float u6 = fmaxf(dcur[12], dcur[13]), u7 = fmaxf(dcur[14], dcur[15]);
    float mx = fmaxf(fmaxf(fmaxf(u0, u1), fmaxf(u2, u3)),
                     fmaxf(fmaxf(u4, u5), fmaxf(u6, u7)));
    {                                           // cross-half max (order-robust)
      float mc = mx;
      pl32swapf(mc, mx);
      mx = fmaxf(mc, mx);
    }
    if (__any(mx > m + 12.f)) {                 // defer-max (THR=12 log2)
      float mnew = fmaxf(m, mx);
      float alpha = __builtin_exp2f(m - mnew);
      m = mnew;
      lsum *= alpha;
#pragma unroll
      for (int ct = 0; ct < 4; ++ct)
#pragma unroll
        for (int r = 0; r < 16; ++r) acc[ct][r] *= alpha;
    }
    float p[16];
#pragma unroll
    for (int r = 0; r < 16; ++r) p[r] = __builtin_exp2f(dcur[r] - m);
    float cs = 0.f;
#pragma unroll
    for (int r = 0; r < 16; ++r) cs += p[r];
    lsum += cs;                                 // per-half partial (no shfl)

    // ---- P -> B-frags: swap(A0,A2) yields (pb0.u[0], pb0.u[2]) etc ----
    unsigned A0 = pk2(p[0], p[1]), A1 = pk2(p[2], p[3]);
    unsigned A2 = pk2(p[4], p[5]), A3 = pk2(p[6], p[7]);
    unsigned A4 = pk2(p[8], p[9]), A5 = pk2(p[10], p[11]);
    unsigned A6 = pk2(p[12], p[13]), A7 = pk2(p[14], p[15]);
    pl32swap(A0, A2);
    pl32swap(A1, A3);
    pl32swap(A4, A6);
    pl32swap(A5, A7);
    union { unsigned u[4]; f16x8 v; } pb0, pb1;
    pb0.u[0] = A0; pb0.u[1] = A1; pb0.u[2] = A2; pb0.u[3] = A3;
    pb1.u[0] = A4; pb1.u[1] = A5; pb1.u[2] = A6; pb1.u[3] = A7;

    // ---- PV: 4 c-tiles of this wave's c-half, V from registers ----
    __builtin_amdgcn_s_setprio(1);
    acc[0] = MFMA32(vf[0], pb0.v, acc[0]);
    acc[0] = MFMA32(vf[1], pb1.v, acc[0]);
    acc[1] = MFMA32(vf[2], pb0.v, acc[1]);
    acc[1] = MFMA32(vf[3], pb1.v, acc[1]);
    acc[2] = MFMA32(vf[4], pb0.v, acc[2]);
    acc[2] = MFMA32(vf[5], pb1.v, acc[2]);
    acc[3] = MFMA32(vf[6], pb0.v, acc[3]);
    acc[3] = MFMA32(vf[7], pb1.v, acc[3]);
    __builtin_amdgcn_s_setprio(0);
  };

  f32x16 dA = qkt(0), dB;                       // scores for tile 0
  for (int t = 0; t < NT; t += 2) {             // NT even: no tail
    body(t, dA, dB);
    body(t + 1, dB, dA);
  }

  // ---- epilogue: combine half-sums (order-robust), O_s = acc/lsum ----
  {
    float lc = lsum;
    pl32swapf(lc, lsum);
    lsum += lc;
  }
  const float rl = 1.f / lsum;
  unsigned short* Pb = P + (size_t)(s * Bn + b) * Cn * Nn;
#pragma unroll
  for (int ct = 0; ct < 4; ++ct)
#pragma unroll
    for (int r = 0; r < 16; ++r) {
      int c = 32 * (chalf * 4 + ct) + (r & 3) + 8 * (r >> 2) + 4 * hi;
      Pb[(size_t)c * Nn + q0 + q] = f2h(acc[ct][r] * rl);
    }
  if (!hi && !chalf)
    *(float2*)&ml[((size_t)(s * Bn + b) * Nn + q0 + q) * 2] = make_float2(m, lsum);
}

// ---------------- combine partials + residual ----------------
// out = x + sum_s w_s * O_s,  w_s = 2^(m_s - M) * l_s / sum(2^(m_s-M) l_s).
__global__ __launch_bounds__(256) void combine_k(
    const float* __restrict__ x, const unsigned short* __restrict__ P,
    const float* __restrict__ ml, float* __restrict__ out, int splits) {
  __shared__ float sc[4][32];
  const int tpb = Nn / 32;                      // 72
  const int b = blockIdx.x / tpb;
  const int n0 = (blockIdx.x - b * tpb) * 32;
  const int t = threadIdx.x;
  if (t < 32) {
    const int n = n0 + t;
    const size_t sstr = (size_t)Bn * Nn * 2;
    const float* mlb = ml + ((size_t)b * Nn + n) * 2;
    float m0 = mlb[0], l0 = mlb[1];
    float m1 = -1e30f, l1 = 0.f, m2 = -1e30f, l2 = 0.f, m3 = -1e30f, l3 = 0.f;
    if (splits > 1) { m1 = mlb[sstr]; l1 = mlb[sstr + 1]; }
    if (splits > 2) { m2 = mlb[2 * sstr]; l2 = mlb[2 * sstr + 1]; }
    if (splits > 3) { m3 = mlb[3 * sstr]; l3 = mlb[3 * sstr + 1]; }
    float M = fmaxf(fmaxf(m0, m1), fmaxf(m2, m3));
    float g0 = __builtin_exp2f(m0 - M) * l0, g1 = __builtin_exp2f(m1 - M) * l1;
    float g2 = __builtin_exp2f(m2 - M) * l2, g3 = __builtin_exp2f(m3 - M) * l3;
    float rden = 1.f / (g0 + g1 + g2 + g3);
    sc[0][t] = g0 * rden; sc[1][t] = g1 * rden;
    sc[2][t] = g2 * rden; sc[3][t] = g3 * rden;
  }
  __syncthreads();
  const int nl4 = (t & 7) * 4, c0 = t >> 3;
  const size_t pstr = (size_t)Bn * Cn * Nn;     // shorts per split
  const float* xb = x + (size_t)b * Cn * Nn;
  float* ob = out + (size_t)b * Cn * Nn;
#pragma unroll
  for (int k = 0; k < 8; ++k) {
    const int c = c0 + 32 * k;
    const unsigned short* Pp = P + ((size_t)b * Cn + c) * Nn + n0 + nl4;
    f32x4 a = {0.f, 0.f, 0.f, 0.f};
    for (int s2 = 0; s2 < splits; ++s2) {
      ushort4 ph = *(const ushort4*)(Pp + s2 * pstr);
      f32x4 pv = {h2f(ph.x), h2f(ph.y), h2f(ph.z), h2f(ph.w)};
      f32x4 sw = {sc[s2][nl4 + 0], sc[s2][nl4 + 1], sc[s2][nl4 + 2], sc[s2][nl4 + 3]};
      a += sw * pv;
    }
    f32x4 xv = *(const f32x4*)(xb + (size_t)c * Nn + n0 + nl4);
    *(f32x4*)(ob + (size_t)c * Nn + n0 + nl4) = xv + a;
  }
}

extern "C" void kernel_launch(void* const* d_in, const int* in_sizes, int n_in,
                              void* d_out, int out_size, void* d_ws, size_t ws_size,
                              hipStream_t stream) {
  const float* x = (const float*)d_in[0];
  const float* wq = (const float*)d_in[1];
  const float* wk = (const float*)d_in[2];
  const float* wv = (const float*)d_in[3];
  float* out = (float*)d_out;

  unsigned short* wqb = (unsigned short*)d_ws;
  unsigned short* wkb = wqb + Cn * Cn;
  unsigned short* wvb = wkb + Cn * Cn;
  unsigned short* Qt = wvb + Cn * Cn;
  unsigned short* Ksw = Qt + (size_t)Bn * Nn * Cn;
  unsigned short* Vsw = Ksw + (size_t)Bn * Nn * Cn;
  unsigned short* P = Vsw + (size_t)Bn * Nn * Cn;

  const size_t baseB = (size_t)(3 * Cn * Cn + 3 * (size_t)Bn * Nn * Cn) * 2;
  const size_t perSplitB = (size_t)Bn * Nn * Cn * 2 + (size_t)Bn * Nn * 2 * 4;

  int splits = 1;
  if (baseB + 4 * perSplitB <= ws_size) splits = 4;
  else if (baseB + 2 * perSplitB <= ws_size) splits = 2;

  float* ml = (float*)(P + (size_t)splits * Bn * Nn * Cn);

  hipLaunchKernelGGL(cvt_w, dim3(3 * Cn * Cn / 256), dim3(256), 0, stream, wq, wk, wv, wqb);
  hipLaunchKernelGGL(qkv_proj, dim3(Nn / 32, Bn), dim3(256), 0, stream,
                     x, wqb, wkb, wvb, Qt, Ksw, Vsw);
  hipLaunchKernelGGL(attn_split, dim3(Bn * splits * 36), dim3(256), 0, stream,
                     Qt, Ksw, Vsw, P, ml, splits);
  hipLaunchKernelGGL(combine_k, dim3(Bn * Nn / 32), dim3(256), 0, stream,
                     x, P, ml, out, splits);
}